// Round 13
// baseline (440.981 us; speedup 1.0000x reference)
//
#include <hip/hip_runtime.h>
#include <hip/hip_bf16.h>

typedef __attribute__((ext_vector_type(8))) short bf16x8;
typedef __attribute__((ext_vector_type(4))) float f32x4;

#define HID    128
#define KDIM   256   // 2*HID
#define MT     64    // edges per tile

__device__ __forceinline__ unsigned short f2bf(float x) {
    unsigned int u = __float_as_uint(x);
    u += 0x7FFFu + ((u >> 16) & 1u);      // round-to-nearest-even
    return (unsigned short)(u >> 16);
}
__device__ __forceinline__ int pack2(float a, float b) {
    return (int)f2bf(a) | ((int)f2bf(b) << 16);
}
__device__ __forceinline__ float lrelu(float x) { return fmaxf(x, 0.2f * x); }

// ---- fp32 -> bf16 conversion: z + W1 + W2 (grid-stride, vec4) ----
__global__ void convert_all_kernel(const float* __restrict__ z,
                                   const float* __restrict__ W1,
                                   const float* __restrict__ W2,
                                   unsigned short* __restrict__ zb,
                                   unsigned short* __restrict__ w1b,
                                   unsigned short* __restrict__ w2b,
                                   int nz4, int nw14, int nw24) {
    int total = nz4 + nw14 + nw24;
    for (int i = blockIdx.x * blockDim.x + threadIdx.x; i < total;
         i += gridDim.x * blockDim.x) {
        const float4* src;
        unsigned short* dst;
        int j;
        if (i < nz4)             { src = (const float4*)z;  dst = zb;  j = i; }
        else if (i < nz4 + nw14) { src = (const float4*)W1; dst = w1b; j = i - nz4; }
        else                     { src = (const float4*)W2; dst = w2b; j = i - nz4 - nw14; }
        float4 v = src[j];
        ushort4 o;
        o.x = f2bf(v.x); o.y = f2bf(v.y); o.z = f2bf(v.z); o.w = f2bf(v.w);
        *(ushort4*)(dst + (size_t)j * 4) = o;
    }
}

// ---- weights-only conversion (fallback when ws too small for z) ----
__global__ void convert_w_kernel(const float* __restrict__ W1,
                                 const float* __restrict__ W2,
                                 unsigned short* __restrict__ w1b,
                                 unsigned short* __restrict__ w2b,
                                 int nw14, int nw24) {
    int i = blockIdx.x * blockDim.x + threadIdx.x;
    if (i >= nw14 + nw24) return;
    const float4* src;
    unsigned short* dst;
    int j;
    if (i < nw14) { src = (const float4*)W1; dst = w1b; j = i; }
    else          { src = (const float4*)W2; dst = w2b; j = i - nw14; }
    float4 v = src[j];
    ushort4 o;
    o.x = f2bf(v.x); o.y = f2bf(v.y); o.z = f2bf(v.z); o.w = f2bf(v.w);
    *(ushort4*)(dst + (size_t)j * 4) = o;
}

// ---- fused gather + 3-layer MLP, CROSS-TILE PIPELINED ----
// Grid-stride over 64-edge tiles; A double-buffered (X/Y, 2x32KB, LDS=64KB
// exactly -> 2 blocks/CU). While tile t computes on X, staging DMA for t+1
// runs into Y. Raw s_barrier + counted waits (m201 pattern): no implicit
// vmcnt(0) drain at barriers. VMEM issue order per iter (FIFO-safe):
//   ei(t+1) -> W1 frags (awaited in L1) -> W2 frags (awaited in L2, counted)
//   -> staging(8, awaited only at next B0) -> out store.
// W2 preloaded to REGISTERS before staging issue so no later load-wait
// drains the staging (vmcnt is FIFO).
// Phases: B0(vmcnt0+bar) L1[X] W2pre stage->Y B1(bar) epi h1->X
//         B2(lgkm+bar) L2[X] B2.5(bar) partials->X[0:1K] B3(lgkm+bar) out.
// R12: 342us @ 4 blk/CU, MfmaUtil 20% — gather drain ~4k cyc exposed/tile.
// R11: halved tiles/8 waves = dilution (634). R8: no-LDS gather = 561.
template <bool ZB>
__global__ __launch_bounds__(256, 2)
void disc_kernel(const float* __restrict__ z,
                 const unsigned short* __restrict__ zb,
                 const int* __restrict__ ei,         // int32 per harness contract
                 const unsigned short* __restrict__ w1b,
                 const float* __restrict__ b1,
                 const unsigned short* __restrict__ w2b,
                 const float* __restrict__ b2,
                 const float* __restrict__ W3,
                 const float* __restrict__ b3,
                 float* __restrict__ out, int E) {
    __shared__ __align__(16) unsigned char smem[65536];   // X(32K) | Y(32K)

    const int tid  = threadIdx.x;
    const int wave = tid >> 6;
    const int lane = tid & 63;
    const int lr   = lane & 15;
    const int lk   = lane >> 4;
    const float b3s = b3[0];
    const int ntiles = (E + MT - 1) / MT;
    const int stride = gridDim.x;

    // tile-invariant weight bases
    const int n0 = wave * 64;
    const unsigned short* wbase  = w1b + (size_t)(n0 + lr) * KDIM + lk * 8;
    const int c2 = wave * 16 + lr;
    const unsigned short* w2base = w2b + (size_t)c2 * KDIM + lk * 8;

    int sArr[8], dArr[8];

    auto load_ei = [&](int t) {
        if constexpr (ZB) {
            #pragma unroll
            for (int tt = 0; tt < 8; ++tt) {
                int row = wave * 16 + tt * 2 + (lane >> 5);
                int e = t * MT + row; if (e >= E) e = E - 1;
                sArr[tt] = ei[e];
                dArr[tt] = ei[E + e];
            }
        } else {
            int r = tid >> 2;
            int e = t * MT + r; if (e >= E) e = E - 1;
            sArr[0] = ei[e];
            dArr[0] = ei[E + e];
        }
    };

    auto stage = [&](unsigned char* base) {
        if constexpr (ZB) {
            #pragma unroll
            for (int tt = 0; tt < 8; ++tt) {
                int row = wave * 16 + tt * 2 + (lane >> 5);
                int c = (lane & 31) ^ (row & 7);     // pre-swizzled source chunk
                int node = (c < 16) ? sArr[tt] : dArr[tt];
                const unsigned short* g = zb + (size_t)node * HID + (c & 15) * 8;
                __builtin_amdgcn_global_load_lds(
                    (const __attribute__((address_space(1))) unsigned int*)g,
                    (__attribute__((address_space(3))) unsigned int*)(base + wave * 8192 + tt * 1024),
                    16, 0, 0);
            }
        } else {
            int r = tid >> 2, q = tid & 3;
            const float4* zs = (const float4*)(z + (size_t)sArr[0] * HID);
            const float4* zd = (const float4*)(z + (size_t)dArr[0] * HID);
            const int swz = (r & 7) << 4;
            #pragma unroll
            for (int j = 0; j < 8; ++j) {
                int c = q * 8 + j;
                const float4* src = (c < 16) ? (zs + c * 2) : (zd + (c - 16) * 2);
                float4 v0 = src[0], v1 = src[1];
                int4 o;
                o.x = pack2(v0.x, v0.y);
                o.y = pack2(v0.z, v0.w);
                o.z = pack2(v1.x, v1.y);
                o.w = pack2(v1.z, v1.w);
                *(int4*)(base + r * 512 + ((c * 16) ^ swz)) = o;
            }
        }
    };

    int tile = blockIdx.x;
    if (tile >= ntiles) return;

    // prologue: stage first tile into buffer 0
    load_ei(tile);
    stage(smem);
    int cur = 0;

    for (;;) {
        unsigned char* X = smem + (cur << 15);
        unsigned char* Y = smem + ((cur ^ 1) << 15);
        const int e0 = tile * MT;

        // B0: staging of X (and prev out-store) complete; all waves synced.
        asm volatile("s_waitcnt vmcnt(0) lgkmcnt(0)" ::: "memory");
        __builtin_amdgcn_s_barrier();
        __builtin_amdgcn_sched_barrier(0);

        const int ntile = tile + stride;
        const bool has = ntile < ntiles;
        if (has) load_ei(ntile);          // early; forced done by W1-frag waits

        // ---- layer 1: h1[64 x 256] = A @ W1^T, wave owns 64 W1-cols ----
        f32x4 acc[4][4];
        #pragma unroll
        for (int mi = 0; mi < 4; ++mi)
            #pragma unroll
            for (int ni = 0; ni < 4; ++ni)
                acc[mi][ni] = (f32x4){0.f, 0.f, 0.f, 0.f};

        bf16x8 bcur[4], bnxt[4];
        #pragma unroll
        for (int ni = 0; ni < 4; ++ni)
            bcur[ni] = *(const bf16x8*)(wbase + (size_t)ni * 16 * KDIM);

        #pragma unroll
        for (int ks = 0; ks < 8; ++ks) {
            if (ks < 7) {
                #pragma unroll
                for (int ni = 0; ni < 4; ++ni)
                    bnxt[ni] = *(const bf16x8*)(wbase + (size_t)ni * 16 * KDIM + (ks + 1) * 32);
            }
            const int kb = ks * 64 + lk * 16;
            bf16x8 a[4];
            #pragma unroll
            for (int mi = 0; mi < 4; ++mi) {
                int row = mi * 16 + lr;
                a[mi] = *(const bf16x8*)(X + row * 512 + (kb ^ ((row & 7) << 4)));
            }
            #pragma unroll
            for (int mi = 0; mi < 4; ++mi)
                #pragma unroll
                for (int ni = 0; ni < 4; ++ni)
                    acc[mi][ni] = __builtin_amdgcn_mfma_f32_16x16x32_bf16(
                        bcur[ni], a[mi], acc[mi][ni], 0, 0, 0);   // reg-dim = W1 col
            if (ks < 7) {
                #pragma unroll
                for (int ni = 0; ni < 4; ++ni) bcur[ni] = bnxt[ni];
            }
        }

        // preload ALL W2 fragments to registers (their waits happen in L2 with
        // counted vmcnt; issued BEFORE staging so no wait drains the staging)
        bf16x8 w2r[8];
        #pragma unroll
        for (int ks = 0; ks < 8; ++ks)
            w2r[ks] = *(const bf16x8*)(w2base + ks * 32);

        // issue staging for next tile into Y (in flight until next B0)
        if (has) stage(Y);

        // B1: all waves done reading X -> safe to overwrite with h1
        asm volatile("" ::: "memory");
        __builtin_amdgcn_s_barrier();
        __builtin_amdgcn_sched_barrier(0);

        // epilogue: bias + leaky -> h1 bf16 into X (packed 8B, swizzled)
        #pragma unroll
        for (int ni = 0; ni < 4; ++ni) {
            int colb = n0 + ni * 16 + lk * 4;
            float4 bias = *(const float4*)(b1 + colb);
            #pragma unroll
            for (int mi = 0; mi < 4; ++mi) {
                int row = mi * 16 + lr;
                float x0 = lrelu(acc[mi][ni][0] + bias.x);
                float x1 = lrelu(acc[mi][ni][1] + bias.y);
                float x2 = lrelu(acc[mi][ni][2] + bias.z);
                float x3 = lrelu(acc[mi][ni][3] + bias.w);
                int2 o;
                o.x = pack2(x0, x1);
                o.y = pack2(x2, x3);
                *(int2*)(X + row * 512 + ((colb * 2) ^ ((row & 7) << 4))) = o;
            }
        }

        // B2: h1 writes visible
        asm volatile("s_waitcnt lgkmcnt(0)" ::: "memory");
        __builtin_amdgcn_s_barrier();
        __builtin_amdgcn_sched_barrier(0);

        // ---- layer 2: [64 x 64] = h1 @ W2^T, wave owns 16 W2-cols ----
        f32x4 acc2[4];
        #pragma unroll
        for (int mi = 0; mi < 4; ++mi) acc2[mi] = (f32x4){0.f, 0.f, 0.f, 0.f};
        #pragma unroll
        for (int ks = 0; ks < 8; ++ks) {
            const int kb = ks * 64 + lk * 16;
            bf16x8 a2[4];
            #pragma unroll
            for (int mi = 0; mi < 4; ++mi) {
                int row = mi * 16 + lr;
                a2[mi] = *(const bf16x8*)(X + row * 512 + (kb ^ ((row & 7) << 4)));
            }
            #pragma unroll
            for (int mi = 0; mi < 4; ++mi)
                acc2[mi] = __builtin_amdgcn_mfma_f32_16x16x32_bf16(
                    w2r[ks], a2[mi], acc2[mi], 0, 0, 0);  // reg-dim = W2 col
        }

        // B2.5: all h1 reads done -> partials may alias X[0:1KB]
        asm volatile("" ::: "memory");
        __builtin_amdgcn_s_barrier();
        __builtin_amdgcn_sched_barrier(0);

        // ---- layer 3 fused: partial = sum_c lrelu(h2)*W3[c] -> X[0:1KB] ----
        float* part = (float*)X;
        {
            int colb = wave * 16 + lk * 4;
            float4 b2v = *(const float4*)(b2 + colb);
            float4 w3v = *(const float4*)(W3 + colb);
            #pragma unroll
            for (int mi = 0; mi < 4; ++mi) {
                float s = lrelu(acc2[mi][0] + b2v.x) * w3v.x
                        + lrelu(acc2[mi][1] + b2v.y) * w3v.y
                        + lrelu(acc2[mi][2] + b2v.z) * w3v.z
                        + lrelu(acc2[mi][3] + b2v.w) * w3v.w;
                s += __shfl_xor(s, 16);
                s += __shfl_xor(s, 32);
                if (lk == 0) part[wave * 64 + mi * 16 + lr] = s;
            }
        }

        // B3: partials visible
        asm volatile("s_waitcnt lgkmcnt(0)" ::: "memory");
        __builtin_amdgcn_s_barrier();
        __builtin_amdgcn_sched_barrier(0);

        if (tid < MT) {
            int e = e0 + tid;
            float s = part[tid] + part[64 + tid] + part[128 + tid] + part[192 + tid] + b3s;
            if (e < E) out[e] = s;
        }

        if (!has) break;
        tile = ntile;
        cur ^= 1;
    }
}

extern "C" void kernel_launch(void* const* d_in, const int* in_sizes, int n_in,
                              void* d_out, int out_size, void* d_ws, size_t ws_size,
                              hipStream_t stream) {
    const float* z  = (const float*)d_in[0];
    const int*   ei = (const int*)d_in[1];
    const float* W1 = (const float*)d_in[2];
    const float* b1 = (const float*)d_in[3];
    const float* W2 = (const float*)d_in[4];
    const float* b2 = (const float*)d_in[5];
    const float* W3 = (const float*)d_in[6];
    const float* b3 = (const float*)d_in[7];
    float* out = (float*)d_out;

    const int nz  = in_sizes[0];       // 12,800,000
    const int E   = in_sizes[1] / 2;   // 1,000,000
    const int nw1 = in_sizes[2];       // 65,536
    const int nw2 = in_sizes[4];       // 16,384

    const size_t need_full = (size_t)(nz + nw1 + nw2) * 2;
    const bool zb_ok = ws_size >= need_full;

    const int grid = 512;              // 2 blocks/CU resident, grid-stride tiles

    if (zb_ok) {
        unsigned short* zbp = (unsigned short*)d_ws;
        unsigned short* w1b = zbp + nz;
        unsigned short* w2b = w1b + nw1;
        convert_all_kernel<<<2048, 256, 0, stream>>>(z, W1, W2, zbp, w1b, w2b,
                                                     nz / 4, nw1 / 4, nw2 / 4);
        disc_kernel<true><<<grid, 256, 0, stream>>>(z, zbp, ei, w1b, b1, w2b,
                                                    b2, W3, b3, out, E);
    } else {
        unsigned short* w1b = (unsigned short*)d_ws;
        unsigned short* w2b = w1b + nw1;
        const int ntot = (nw1 + nw2) / 4;
        convert_w_kernel<<<(ntot + 255) / 256, 256, 0, stream>>>(W1, W2, w1b, w2b,
                                                                 nw1 / 4, nw2 / 4);
        disc_kernel<false><<<grid, 256, 0, stream>>>(z, (const unsigned short*)nullptr,
                                                     ei, w1b, b1, w2b, b2, W3, b3,
                                                     out, E);
    }
}